// Round 1
// baseline (337.629 us; speedup 1.0000x reference)
//
#include <hip/hip_runtime.h>
#include <hip/hip_bf16.h>
#include <stdint.h>

#define MDIM 4096
#define NDIM 4096
#define KDIM 4096
#define BM 128
#define BN 128
#define BK 32

typedef __attribute__((ext_vector_type(8))) short bf16x8;      // 8 bf16 = 4 VGPRs (MFMA A/B frag)
typedef __attribute__((ext_vector_type(4))) float floatx4;     // MFMA C/D frag
typedef __attribute__((ext_vector_type(8))) unsigned short ushort8_t;

// fp32 -> bf16 round-to-nearest-even
__device__ __forceinline__ unsigned short f2bf(float f) {
  union { float f; uint32_t u; } v; v.f = f;
  uint32_t u = v.u;
  u += 0x7FFFu + ((u >> 16) & 1u);
  return (unsigned short)(u >> 16);
}

// async global->LDS, 16B per lane. LDS dest is wave-uniform base + lane*16;
// our layout guarantees lds byte offset == tid*16 within each issue.
__device__ __forceinline__ void async_copy16(unsigned short* lds, const unsigned short* g) {
  __builtin_amdgcn_global_load_lds((const __attribute__((address_space(1))) void*)g,
                                   (__attribute__((address_space(3))) void*)lds,
                                   16, 0, 0);
}

// ---------------- fp32 -> bf16 conversion into workspace ----------------
__global__ __launch_bounds__(256) void convert_bf16(const float* __restrict__ x,
                                                    const float* __restrict__ w,
                                                    unsigned short* __restrict__ xb,
                                                    unsigned short* __restrict__ wb) {
  const int64_t n4 = (int64_t)MDIM * KDIM / 4;   // float4 groups per matrix
  int64_t i = (int64_t)blockIdx.x * 256 + threadIdx.x;
  const float4* src;
  unsigned short* dst;
  if (i < n4) { src = (const float4*)x; dst = xb; }
  else        { src = (const float4*)w; dst = wb; i -= n4; }
  float4 v = src[i];
  ushort4 o;
  o.x = f2bf(v.x); o.y = f2bf(v.y); o.z = f2bf(v.z); o.w = f2bf(v.w);
  *(ushort4*)(dst + i * 4) = o;
}

// ---------------- main bf16 MFMA GEMM (m97 structure) ----------------
// C[m,n] = sum_k A[m,k]*B[n,k] + bias[n];  A,B bf16 row-major K-contiguous.
__global__ __launch_bounds__(256) void gemm_bf16(const unsigned short* __restrict__ A,
                                                 const unsigned short* __restrict__ B,
                                                 const float* __restrict__ bias,
                                                 float* __restrict__ C) {
  __shared__ __align__(16) unsigned short As[BM * BK];  // 8 KB
  __shared__ __align__(16) unsigned short Bs[BN * BK];  // 8 KB
  const int tid = threadIdx.x;
  const int bm = blockIdx.y, bn = blockIdx.x;
  const int lane = tid & 63, wave = tid >> 6;
  const int quad = lane >> 4, r16 = lane & 15;
  const int wm = (wave >> 1) * 64, wn = (wave & 1) * 64;  // wave tile origin (64x64)

  // staging: thread t covers row (t>>2), 16B chunk (t&3) of the 64B row; two issues = rows 0..63 / 64..127
  const int srow = tid >> 2;
  const int scol = (tid & 3) * 8;  // element offset in K
  const unsigned short* ag0 = A + (int64_t)(bm * BM + srow) * KDIM + scol;
  const unsigned short* ag1 = ag0 + (int64_t)64 * KDIM;
  const unsigned short* bg0 = B + (int64_t)(bn * BN + srow) * KDIM + scol;
  const unsigned short* bg1 = bg0 + (int64_t)64 * KDIM;
  unsigned short* al0 = As + tid * 8;          // byte offset tid*16
  unsigned short* al1 = As + 2048 + tid * 8;
  unsigned short* bl0 = Bs + tid * 8;
  unsigned short* bl1 = Bs + 2048 + tid * 8;

  floatx4 acc[4][4] = {};

  for (int k0 = 0; k0 < KDIM; k0 += BK) {
    async_copy16(al0, ag0 + k0);
    async_copy16(al1, ag1 + k0);
    async_copy16(bl0, bg0 + k0);
    async_copy16(bl1, bg1 + k0);
    __syncthreads();  // compiler drains vmcnt before s_barrier (m97 semantics)

    bf16x8 a[4], b[4];
#pragma unroll
    for (int i = 0; i < 4; ++i)
      a[i] = *(const bf16x8*)(As + (wm + i * 16 + r16) * BK + quad * 8);
#pragma unroll
    for (int i = 0; i < 4; ++i)
      b[i] = *(const bf16x8*)(Bs + (wn + i * 16 + r16) * BK + quad * 8);

#pragma unroll
    for (int i = 0; i < 4; ++i)
#pragma unroll
      for (int j = 0; j < 4; ++j)
        acc[i][j] = __builtin_amdgcn_mfma_f32_16x16x32_bf16(a[i], b[j], acc[i][j], 0, 0, 0);

    __syncthreads();  // protect LDS against next iteration's staging
  }

  // epilogue: C/D layout col = lane&15, row = quad*4 + r (m89-verified)
  const int col0 = bn * BN + wn + r16;
  const int row0 = bm * BM + wm + quad * 4;
#pragma unroll
  for (int j = 0; j < 4; ++j) {
    const float bv = bias[col0 + j * 16];
#pragma unroll
    for (int i = 0; i < 4; ++i) {
      float* cp = C + (int64_t)(row0 + i * 16) * NDIM + col0 + j * 16;
#pragma unroll
      for (int r = 0; r < 4; ++r)
        cp[(int64_t)r * NDIM] = acc[i][j][r] + bv;
    }
  }
}

// ---------------- fallback: fp32 inputs, convert in staging (no workspace) ----------------
__global__ __launch_bounds__(256) void gemm_f32in(const float* __restrict__ A,
                                                  const float* __restrict__ W,
                                                  const float* __restrict__ bias,
                                                  float* __restrict__ C) {
  __shared__ __align__(16) unsigned short As[BM * BK];
  __shared__ __align__(16) unsigned short Bs[BN * BK];
  const int tid = threadIdx.x;
  const int bm = blockIdx.y, bn = blockIdx.x;
  const int lane = tid & 63, wave = tid >> 6;
  const int quad = lane >> 4, r16 = lane & 15;
  const int wm = (wave >> 1) * 64, wn = (wave & 1) * 64;

  const int srow = tid >> 1;          // 128 rows, 2 threads/row
  const int scol = (tid & 1) * 16;    // 16 floats each
  const float* ag = A + (int64_t)(bm * BM + srow) * KDIM + scol;
  const float* bg = W + (int64_t)(bn * BN + srow) * KDIM + scol;
  unsigned short* al = As + srow * BK + scol;
  unsigned short* bl = Bs + srow * BK + scol;

  floatx4 acc[4][4] = {};
  for (int k0 = 0; k0 < KDIM; k0 += BK) {
    float4 a0 = *(const float4*)(ag + k0);
    float4 a1 = *(const float4*)(ag + k0 + 4);
    float4 a2 = *(const float4*)(ag + k0 + 8);
    float4 a3 = *(const float4*)(ag + k0 + 12);
    float4 b0 = *(const float4*)(bg + k0);
    float4 b1 = *(const float4*)(bg + k0 + 4);
    float4 b2 = *(const float4*)(bg + k0 + 8);
    float4 b3 = *(const float4*)(bg + k0 + 12);
    ushort8_t pa0 = {f2bf(a0.x), f2bf(a0.y), f2bf(a0.z), f2bf(a0.w),
                     f2bf(a1.x), f2bf(a1.y), f2bf(a1.z), f2bf(a1.w)};
    ushort8_t pa1 = {f2bf(a2.x), f2bf(a2.y), f2bf(a2.z), f2bf(a2.w),
                     f2bf(a3.x), f2bf(a3.y), f2bf(a3.z), f2bf(a3.w)};
    ushort8_t pb0 = {f2bf(b0.x), f2bf(b0.y), f2bf(b0.z), f2bf(b0.w),
                     f2bf(b1.x), f2bf(b1.y), f2bf(b1.z), f2bf(b1.w)};
    ushort8_t pb1 = {f2bf(b2.x), f2bf(b2.y), f2bf(b2.z), f2bf(b2.w),
                     f2bf(b3.x), f2bf(b3.y), f2bf(b3.z), f2bf(b3.w)};
    *(ushort8_t*)al = pa0;
    *(ushort8_t*)(al + 8) = pa1;
    *(ushort8_t*)bl = pb0;
    *(ushort8_t*)(bl + 8) = pb1;
    __syncthreads();

    bf16x8 a[4], b[4];
#pragma unroll
    for (int i = 0; i < 4; ++i)
      a[i] = *(const bf16x8*)(As + (wm + i * 16 + r16) * BK + quad * 8);
#pragma unroll
    for (int i = 0; i < 4; ++i)
      b[i] = *(const bf16x8*)(Bs + (wn + i * 16 + r16) * BK + quad * 8);
#pragma unroll
    for (int i = 0; i < 4; ++i)
#pragma unroll
      for (int j = 0; j < 4; ++j)
        acc[i][j] = __builtin_amdgcn_mfma_f32_16x16x32_bf16(a[i], b[j], acc[i][j], 0, 0, 0);
    __syncthreads();
  }

  const int col0 = bn * BN + wn + r16;
  const int row0 = bm * BM + wm + quad * 4;
#pragma unroll
  for (int j = 0; j < 4; ++j) {
    const float bv = bias[col0 + j * 16];
#pragma unroll
    for (int i = 0; i < 4; ++i) {
      float* cp = C + (int64_t)(row0 + i * 16) * NDIM + col0 + j * 16;
#pragma unroll
      for (int r = 0; r < 4; ++r)
        cp[(int64_t)r * NDIM] = acc[i][j][r] + bv;
    }
  }
}

extern "C" void kernel_launch(void* const* d_in, const int* in_sizes, int n_in,
                              void* d_out, int out_size, void* d_ws, size_t ws_size,
                              hipStream_t stream) {
  const float* x    = (const float*)d_in[0];   // [4096, 4096]
  const float* w    = (const float*)d_in[1];   // [4096, 4096]
  const float* bias = (const float*)d_in[2];   // [4096]
  float* out = (float*)d_out;

  dim3 grid(NDIM / BN, MDIM / BM);  // 32 x 32 = 1024 blocks
  const size_t need = (size_t)2 * MDIM * KDIM * sizeof(unsigned short);  // 64 MB
  if (ws_size >= need) {
    unsigned short* xb = (unsigned short*)d_ws;
    unsigned short* wb = xb + (size_t)MDIM * KDIM;
    const int64_t total4 = (int64_t)2 * MDIM * KDIM / 4;
    convert_bf16<<<(int)(total4 / 256), 256, 0, stream>>>(x, w, xb, wb);
    gemm_bf16<<<grid, 256, 0, stream>>>(xb, wb, bias, out);
  } else {
    gemm_f32in<<<grid, 256, 0, stream>>>(x, w, bias, out);
  }
}

// Round 2
// 305.198 us; speedup vs baseline: 1.1063x; 1.1063x over previous
//
#include <hip/hip_runtime.h>
#include <hip/hip_bf16.h>
#include <stdint.h>

#define MDIM 4096
#define NDIM 4096
#define KDIM 4096
#define BM 128
#define BN 128
#define BK 64   // K-tile per barrier pair (2 MFMA k-steps)

typedef __attribute__((ext_vector_type(8))) short bf16x8;      // MFMA A/B frag (4 VGPRs)
typedef __attribute__((ext_vector_type(4))) float floatx4;     // MFMA C/D frag
typedef __attribute__((ext_vector_type(8))) unsigned short ushort8_t;

// fp32 -> bf16 round-to-nearest-even
__device__ __forceinline__ unsigned short f2bf(float f) {
  union { float f; uint32_t u; } v; v.f = f;
  uint32_t u = v.u;
  u += 0x7FFFu + ((u >> 16) & 1u);
  return (unsigned short)(u >> 16);
}

// async global->LDS, 16B/lane. LDS dest = wave-uniform base + lane*16 (m104/m108);
// every use below keeps lds byte offset == tid*16 within the issue.
__device__ __forceinline__ void async_copy16(unsigned short* lds, const unsigned short* g) {
  __builtin_amdgcn_global_load_lds((const __attribute__((address_space(1))) void*)g,
                                   (__attribute__((address_space(3))) void*)lds,
                                   16, 0, 0);
}

// ---------------- fp32 -> bf16 conversion into workspace ----------------
// One thread: 8 floats of x AND 8 floats of w (two independent load streams
// in flight), 16B stores. Exact cover: 8192 blocks x 256 thr x 8 = 16.7M.
__global__ __launch_bounds__(256) void convert_bf16(const float* __restrict__ x,
                                                    const float* __restrict__ w,
                                                    unsigned short* __restrict__ xb,
                                                    unsigned short* __restrict__ wb) {
  const int64_t off = ((int64_t)blockIdx.x * 256 + threadIdx.x) * 8;
  float4 v0 = *(const float4*)(x + off);
  float4 v1 = *(const float4*)(x + off + 4);
  float4 u0 = *(const float4*)(w + off);
  float4 u1 = *(const float4*)(w + off + 4);
  ushort8_t a = {f2bf(v0.x), f2bf(v0.y), f2bf(v0.z), f2bf(v0.w),
                 f2bf(v1.x), f2bf(v1.y), f2bf(v1.z), f2bf(v1.w)};
  ushort8_t b = {f2bf(u0.x), f2bf(u0.y), f2bf(u0.z), f2bf(u0.w),
                 f2bf(u1.x), f2bf(u1.y), f2bf(u1.z), f2bf(u1.w)};
  *(ushort8_t*)(xb + off) = a;
  *(ushort8_t*)(wb + off) = b;
}

// ---------------- main bf16 MFMA GEMM, BK=64, XOR-swizzled LDS ----------------
// C[m,n] = sum_k A[m,k]*B[n,k] + bias[n]; A,B bf16 row-major K-contiguous.
// LDS tile layout: T[row][kc_lds*8..] holds global k-chunk (kc_lds ^ (row&7)).
// Swizzle applied on the GLOBAL fetch side (per-lane addresses are legal there);
// undone in the ds_read index -> quarter-wave bank aliasing 2-way (free, m136).
__global__ __launch_bounds__(256) void gemm_bf16(const unsigned short* __restrict__ A,
                                                 const unsigned short* __restrict__ B,
                                                 const float* __restrict__ bias,
                                                 float* __restrict__ C) {
  __shared__ __align__(16) unsigned short As[BM * BK];  // 16 KB
  __shared__ __align__(16) unsigned short Bs[BN * BK];  // 16 KB
  const int tid = threadIdx.x;
  const int bm = blockIdx.y, bn = blockIdx.x;
  const int lane = tid & 63, wave = tid >> 6;
  const int quad = lane >> 4, r16 = lane & 15;
  const int wm = (wave >> 1) * 64, wn = (wave & 1) * 64;  // wave tile origin (64x64)

  // staging: thread t -> row (t>>3) within a 32-row issue, swizzled 16B k-chunk
  const int srow = tid >> 3;                      // 0..31
  const int kc   = tid & 7;                       // LDS k-chunk slot
  const int kcs  = kc ^ (srow & 7);               // global k-chunk fetched
  const unsigned short* ag = A + (int64_t)(bm * BM + srow) * KDIM + kcs * 8;
  const unsigned short* bg = B + (int64_t)(bn * BN + srow) * KDIM + kcs * 8;
  unsigned short* al = As + tid * 8;              // byte offset tid*16 per issue
  unsigned short* bl = Bs + tid * 8;

  floatx4 acc[4][4] = {};

  for (int k0 = 0; k0 < KDIM; k0 += BK) {
#pragma unroll
    for (int p = 0; p < 4; ++p) {   // 4 issues x 32 rows = 128 rows per matrix
      async_copy16(al + p * 2048, ag + (int64_t)(p * 32) * KDIM + k0);
      async_copy16(bl + p * 2048, bg + (int64_t)(p * 32) * KDIM + k0);
    }
    __syncthreads();  // drains vmcnt (compiler-enforced) — now 1 per 64-K

#pragma unroll
    for (int h = 0; h < 2; ++h) {   // two 32-K MFMA steps per staged tile
      bf16x8 a[4], b[4];
#pragma unroll
      for (int i = 0; i < 4; ++i) {
        const int row = wm + i * 16 + r16;
        const int sw = ((h * 4 + quad) ^ (r16 & 7)) * 8;  // row&7 == r16&7
        a[i] = *(const bf16x8*)(As + row * BK + sw);
      }
#pragma unroll
      for (int i = 0; i < 4; ++i) {
        const int row = wn + i * 16 + r16;
        const int sw = ((h * 4 + quad) ^ (r16 & 7)) * 8;
        b[i] = *(const bf16x8*)(Bs + row * BK + sw);
      }
#pragma unroll
      for (int i = 0; i < 4; ++i)
#pragma unroll
        for (int j = 0; j < 4; ++j)
          acc[i][j] = __builtin_amdgcn_mfma_f32_16x16x32_bf16(a[i], b[j], acc[i][j], 0, 0, 0);
    }
    __syncthreads();  // protect LDS for next staging
  }

  // epilogue: C/D layout col = lane&15, row = quad*4 + r (m89-verified)
  const int col0 = bn * BN + wn + r16;
  const int row0 = bm * BM + wm + quad * 4;
#pragma unroll
  for (int j = 0; j < 4; ++j) {
    const float bv = bias[col0 + j * 16];
#pragma unroll
    for (int i = 0; i < 4; ++i) {
      float* cp = C + (int64_t)(row0 + i * 16) * NDIM + col0 + j * 16;
#pragma unroll
      for (int r = 0; r < 4; ++r)
        cp[(int64_t)r * NDIM] = acc[i][j][r] + bv;
    }
  }
}

// ---------------- fallback: fp32 inputs, convert in staging (no workspace) ----------------
#define FBK 32
__global__ __launch_bounds__(256) void gemm_f32in(const float* __restrict__ A,
                                                  const float* __restrict__ W,
                                                  const float* __restrict__ bias,
                                                  float* __restrict__ C) {
  __shared__ __align__(16) unsigned short As[BM * FBK];
  __shared__ __align__(16) unsigned short Bs[BN * FBK];
  const int tid = threadIdx.x;
  const int bm = blockIdx.y, bn = blockIdx.x;
  const int lane = tid & 63, wave = tid >> 6;
  const int quad = lane >> 4, r16 = lane & 15;
  const int wm = (wave >> 1) * 64, wn = (wave & 1) * 64;

  const int srow = tid >> 1;
  const int scol = (tid & 1) * 16;
  const float* ag = A + (int64_t)(bm * BM + srow) * KDIM + scol;
  const float* bg = W + (int64_t)(bn * BN + srow) * KDIM + scol;
  unsigned short* al = As + srow * FBK + scol;
  unsigned short* bl = Bs + srow * FBK + scol;

  floatx4 acc[4][4] = {};
  for (int k0 = 0; k0 < KDIM; k0 += FBK) {
    float4 a0 = *(const float4*)(ag + k0);
    float4 a1 = *(const float4*)(ag + k0 + 4);
    float4 a2 = *(const float4*)(ag + k0 + 8);
    float4 a3 = *(const float4*)(ag + k0 + 12);
    float4 b0 = *(const float4*)(bg + k0);
    float4 b1 = *(const float4*)(bg + k0 + 4);
    float4 b2 = *(const float4*)(bg + k0 + 8);
    float4 b3 = *(const float4*)(bg + k0 + 12);
    ushort8_t pa0 = {f2bf(a0.x), f2bf(a0.y), f2bf(a0.z), f2bf(a0.w),
                     f2bf(a1.x), f2bf(a1.y), f2bf(a1.z), f2bf(a1.w)};
    ushort8_t pa1 = {f2bf(a2.x), f2bf(a2.y), f2bf(a2.z), f2bf(a2.w),
                     f2bf(a3.x), f2bf(a3.y), f2bf(a3.z), f2bf(a3.w)};
    ushort8_t pb0 = {f2bf(b0.x), f2bf(b0.y), f2bf(b0.z), f2bf(b0.w),
                     f2bf(b1.x), f2bf(b1.y), f2bf(b1.z), f2bf(b1.w)};
    ushort8_t pb1 = {f2bf(b2.x), f2bf(b2.y), f2bf(b2.z), f2bf(b2.w),
                     f2bf(b3.x), f2bf(b3.y), f2bf(b3.z), f2bf(b3.w)};
    *(ushort8_t*)al = pa0;
    *(ushort8_t*)(al + 8) = pa1;
    *(ushort8_t*)bl = pb0;
    *(ushort8_t*)(bl + 8) = pb1;
    __syncthreads();

    bf16x8 a[4], b[4];
#pragma unroll
    for (int i = 0; i < 4; ++i)
      a[i] = *(const bf16x8*)(As + (wm + i * 16 + r16) * FBK + quad * 8);
#pragma unroll
    for (int i = 0; i < 4; ++i)
      b[i] = *(const bf16x8*)(Bs + (wn + i * 16 + r16) * FBK + quad * 8);
#pragma unroll
    for (int i = 0; i < 4; ++i)
#pragma unroll
      for (int j = 0; j < 4; ++j)
        acc[i][j] = __builtin_amdgcn_mfma_f32_16x16x32_bf16(a[i], b[j], acc[i][j], 0, 0, 0);
    __syncthreads();
  }

  const int col0 = bn * BN + wn + r16;
  const int row0 = bm * BM + wm + quad * 4;
#pragma unroll
  for (int j = 0; j < 4; ++j) {
    const float bv = bias[col0 + j * 16];
#pragma unroll
    for (int i = 0; i < 4; ++i) {
      float* cp = C + (int64_t)(row0 + i * 16) * NDIM + col0 + j * 16;
#pragma unroll
      for (int r = 0; r < 4; ++r)
        cp[(int64_t)r * NDIM] = acc[i][j][r] + bv;
    }
  }
}

extern "C" void kernel_launch(void* const* d_in, const int* in_sizes, int n_in,
                              void* d_out, int out_size, void* d_ws, size_t ws_size,
                              hipStream_t stream) {
  const float* x    = (const float*)d_in[0];   // [4096, 4096]
  const float* w    = (const float*)d_in[1];   // [4096, 4096]
  const float* bias = (const float*)d_in[2];   // [4096]
  float* out = (float*)d_out;

  dim3 grid(NDIM / BN, MDIM / BM);  // 32 x 32 = 1024 blocks
  const size_t need = (size_t)2 * MDIM * KDIM * sizeof(unsigned short);  // 64 MB
  if (ws_size >= need) {
    unsigned short* xb = (unsigned short*)d_ws;
    unsigned short* wb = xb + (size_t)MDIM * KDIM;
    convert_bf16<<<8192, 256, 0, stream>>>(x, w, xb, wb);
    gemm_bf16<<<grid, 256, 0, stream>>>(xb, wb, bias, out);
  } else {
    gemm_f32in<<<grid, 256, 0, stream>>>(x, w, bias, out);
  }
}